// Round 3
// baseline (172.756 us; speedup 1.0000x reference)
//
#include <hip/hip_runtime.h>

// DWN pipeline as ONE plain-launch kernel with a hand-rolled grid barrier.
// Round-0/1 evidence: fused-1-dispatch (~39us) and split-4-dispatch (~40us)
// kernel-side times are equal despite wildly different structures, while the
// roofline work is ~5us -> per-dispatch overhead dominates. Round-2's
// cooperative launch never produced a result, so this version gets to one
// dispatch WITHOUT hipLaunchCooperativeKernel: plain <<<256,1024>>> (the
// launch path proven capture-safe in rounds 0/1) + sense-reversing
// device-scope atomic barrier. Co-residency by construction: grid = 256 =
// #CUs, 0 LDS, launch_bounds(1024,4) caps VGPR at 128 -> 1 block/CU fits.
// Spin loop is capped so any residency surprise ends as a wrong answer,
// not a hung container.
//
// Phases (math/order identical to the verified round-1 kernels -> absmax 0):
//   P1: thermometer encode -> transposed bit-pack  bitsT[3072][8] u64
//   P2: layer 1 (pure 6-bit LUT)                   h1T[2000][512] f32
//   P3: layer 2 (6-D multilinear, LSB-first fold)  h2T[1000][512] f32
//   P4: group-sum / tau (exact 10x10 two-level)    out[512][10]

#define FEAT   1024
#define O1     2000
#define O2     1000
#define NCLS   10
#define NB     256
#define NT     1024
#define NWAVES (NB * (NT / 64))   // 4096 global waves

#define WS_BITS_OFF  0
#define WS_H1_OFF    (256 << 10)                 // 256 KB
#define WS_H2_OFF    ((256 << 10) + (4 << 20))   // 256 KB + 4 MB

// Barrier state in __device__ globals: untouched by workspace poisoning,
// and each barrier use leaves {cnt=0, gen+1} -> consistent across replays.
__device__ unsigned g_bar_cnt = 0;
__device__ unsigned g_bar_gen = 0;

__device__ __forceinline__ void grid_barrier() {
    __syncthreads();
    if (threadIdx.x == 0) {
        const unsigned gen =
            __hip_atomic_load(&g_bar_gen, __ATOMIC_RELAXED, __HIP_MEMORY_SCOPE_AGENT);
        const unsigned n =
            __hip_atomic_fetch_add(&g_bar_cnt, 1u, __ATOMIC_ACQ_REL, __HIP_MEMORY_SCOPE_AGENT);
        if (n + 1u == (unsigned)gridDim.x) {
            __hip_atomic_store(&g_bar_cnt, 0u, __ATOMIC_RELAXED, __HIP_MEMORY_SCOPE_AGENT);
            __hip_atomic_fetch_add(&g_bar_gen, 1u, __ATOMIC_ACQ_REL, __HIP_MEMORY_SCOPE_AGENT);
        } else {
            // normal wait is <1us (~hundreds of iters); cap keeps worst case ~0.1s
            for (int spin = 0; spin < (1 << 22); ++spin) {
                if (__hip_atomic_load(&g_bar_gen, __ATOMIC_ACQUIRE,
                                      __HIP_MEMORY_SCOPE_AGENT) != gen) break;
                __builtin_amdgcn_s_sleep(2);
            }
        }
    }
    __syncthreads();
}

__global__ __launch_bounds__(NT, 4) void dwn_onekernel(
    const float* __restrict__ x,       // [512,1024]
    const float* __restrict__ thr,     // [1024,3]
    const float* __restrict__ luts1,   // [2000,64]
    const int*   __restrict__ idx1,    // [2000,6] in [0,3072)
    const float* __restrict__ luts2,   // [1000,64]
    const int*   __restrict__ idx2,    // [1000,6] in [0,2000)
    float* __restrict__ out,           // [512,10]
    unsigned long long* __restrict__ bitsT,  // [3072][8]
    float* __restrict__ h1T,                 // [2000][512]
    float* __restrict__ h2T)                 // [1000][512]
{
    const int t    = threadIdx.x;
    const int lane = t & 63;
    const int wl   = t >> 6;                 // wave in block, 0..15
    const int b    = blockIdx.x;
    const int gw   = (b << 4) | wl;          // global wave id, 0..4095

    // ---- P1: thermometer encode + transposed bit-pack ----
    // Waves 0..7: rows 0..511 for features {4b,4b+1};
    // waves 8..15: same rows for features {4b+2,4b+3}.
    {
        const int w8    = wl & 7;
        const int row   = (w8 << 6) | lane;
        const int fbase = (b << 2) | ((wl >> 3) << 1);
#pragma unroll
        for (int ff = 0; ff < 2; ++ff) {
            const int f = fbase + ff;
            const float xv = x[(size_t)row * FEAT + f];
            const float* tp = thr + (size_t)f * 3;   // wave-uniform
#pragma unroll
            for (int j = 0; j < 3; ++j) {
                unsigned long long m = __ballot(xv > tp[j]);
                if (lane == 0)
                    bitsT[(size_t)(f * 3 + j) * 8 + w8] = m;
            }
        }
    }
    grid_barrier();

    // ---- P2: layer 1 — binary inputs => pure 6-bit table lookup ----
    for (int task = gw; task < O1 * 8; task += NWAVES) {
        const int o = task >> 3;
        const int w = task & 7;
        const int* ip = idx1 + o * 6;        // wave-uniform

        const unsigned long long m0 = bitsT[(size_t)ip[0] * 8 + w];
        const unsigned long long m1 = bitsT[(size_t)ip[1] * 8 + w];
        const unsigned long long m2 = bitsT[(size_t)ip[2] * 8 + w];
        const unsigned long long m3 = bitsT[(size_t)ip[3] * 8 + w];
        const unsigned long long m4 = bitsT[(size_t)ip[4] * 8 + w];
        const unsigned long long m5 = bitsT[(size_t)ip[5] * 8 + w];

        const int code = ((int)((m0 >> lane) & 1ull) << 5)
                       | ((int)((m1 >> lane) & 1ull) << 4)
                       | ((int)((m2 >> lane) & 1ull) << 3)
                       | ((int)((m3 >> lane) & 1ull) << 2)
                       | ((int)((m4 >> lane) & 1ull) << 1)
                       |  (int)((m5 >> lane) & 1ull);

        h1T[(size_t)o * 512 + (w << 6) + lane] = luts1[o * 64 + code];
    }
    grid_barrier();

    // ---- P3: layer 2 — 6-D multilinear interpolation, LSB-first fold ----
    // Arithmetic IDENTICAL (same lerp forms, same fold order) to the verified
    // kernel -> bitwise-equal output.
    for (int task = gw; task < O2 * 8; task += NWAVES) {
        const int o  = task >> 3;
        const int rr = ((task & 7) << 6) | lane;
        const int* ip = idx2 + o * 6;        // wave-uniform

        const float xv0 = h1T[(size_t)ip[0] * 512 + rr];
        const float xv1 = h1T[(size_t)ip[1] * 512 + rr];
        const float xv2 = h1T[(size_t)ip[2] * 512 + rr];
        const float xv3 = h1T[(size_t)ip[3] * 512 + rr];
        const float xv4 = h1T[(size_t)ip[4] * 512 + rr];
        const float xv5 = h1T[(size_t)ip[5] * 512 + rr];

        const float4* lp = (const float4*)(luts2 + (size_t)o * 64);  // uniform row
        float v[16];
#pragma unroll
        for (int q = 0; q < 16; ++q) {       // fold x5 (bit0), x4 (bit1)
            float4 e = lp[q];
            float u0 = e.x + xv5 * (e.y - e.x);
            float u1 = e.z + xv5 * (e.w - e.z);
            v[q] = u0 + xv4 * (u1 - u0);
        }
#pragma unroll
        for (int q = 0; q < 8; ++q) v[q] = v[2*q] + xv3 * (v[2*q+1] - v[2*q]);
#pragma unroll
        for (int q = 0; q < 4; ++q) v[q] = v[2*q] + xv2 * (v[2*q+1] - v[2*q]);
#pragma unroll
        for (int q = 0; q < 2; ++q) v[q] = v[2*q] + xv1 * (v[2*q+1] - v[2*q]);
        h2T[(size_t)o * 512 + rr] = v[0] + xv0 * (v[1] - v[0]);
    }
    grid_barrier();

    // ---- P4: group sum / tau, exact 10x10 two-level order ----
    if (gw < NCLS * 8) {
        const int c  = gw >> 3;
        const int rr = ((gw & 7) << 6) | lane;
        const float* hp = h2T + (size_t)c * 100 * 512 + rr;

        float s = 0.0f;
#pragma unroll
        for (int p = 0; p < 10; ++p) {
            float s2 = 0.0f;
#pragma unroll
            for (int j = 0; j < 10; ++j) s2 += hp[(size_t)(p * 10 + j) * 512];
            s += s2;
        }
        out[rr * NCLS + c] = s / 3.3333333f;
    }
}

extern "C" void kernel_launch(void* const* d_in, const int* in_sizes, int n_in,
                              void* d_out, int out_size, void* d_ws, size_t ws_size,
                              hipStream_t stream) {
    const float* x     = (const float*)d_in[0];
    const float* thr   = (const float*)d_in[1];
    const float* luts1 = (const float*)d_in[2];
    const int*   idx1  = (const int*)  d_in[3];
    const float* luts2 = (const float*)d_in[4];
    const int*   idx2  = (const int*)  d_in[5];
    float* out = (float*)d_out;

    char* ws = (char*)d_ws;
    unsigned long long* bitsT = (unsigned long long*)(ws + WS_BITS_OFF);
    float* h1T = (float*)(ws + WS_H1_OFF);
    float* h2T = (float*)(ws + WS_H2_OFF);

    dwn_onekernel<<<NB, NT, 0, stream>>>(x, thr, luts1, idx1, luts2, idx2,
                                         out, bitsT, h1T, h2T);
}

// Round 4
// 107.747 us; speedup vs baseline: 1.6033x; 1.6033x over previous
//
#include <hip/hip_runtime.h>

// DWN pipeline as ONE plain-launch kernel with a contention-free grid barrier.
//
// Round-3 evidence: the phases cost ~5us (22MB traffic, VALUBusy 3%) but the
// kernel measured 120-125us -> the old barrier (256 same-address agent-scope
// fetch_add ACQ_REL arrivals + acquire-per-poll spinning) cost ~38us/use.
// This version keeps the proven skeleton (grid=256=#CUs, 16 waves/block,
// 0 LDS, plain launch, co-residency verified by occupancy=43.6% + absmax=0)
// and replaces only the barrier protocol:
//   - arrival: ONE release store per block to its OWN flag word (parallel,
//     no RMW serialization; the L2 writeback it triggers is needed anyway
//     to publish h1T/h2T across XCDs)
//   - detection: block 0 wave 0 scans the 256 flags with RELAXED loads
//     (4/lane, wave-parallel, no cache-maintenance), release-stores g_gen
//   - waiters: RELAXED polls of g_gen + s_sleep, then ONE acquire fence
//   - flags/gen are cumulative (base read at launch) -> replay-safe, no
//     reset races; spin caps turn any hang into a visible wrong answer.
// __syncthreads() before arrival drains each wave's vmcnt (compiler emits
// s_waitcnt vmcnt(0) before s_barrier), so the single release fence
// publishes the whole block's stores.
//
// Phases (math/order identical to the verified kernels -> absmax 0):
//   P1: thermometer encode -> transposed bit-pack  bitsT[3072][8] u64
//   P2: layer 1 (pure 6-bit LUT)                   h1T[2000][512] f32
//   P3: layer 2 (6-D multilinear, LSB-first fold)  h2T[1000][512] f32
//   P4: group-sum / tau (exact 10x10 two-level)    out[512][10]

#define FEAT   1024
#define O1     2000
#define O2     1000
#define NCLS   10
#define NB     256
#define NT     1024
#define NWAVES (NB * (NT / 64))   // 4096 global waves

#define WS_BITS_OFF  0
#define WS_H1_OFF    (256 << 10)                 // 256 KB
#define WS_H2_OFF    ((256 << 10) + (4 << 20))   // 256 KB + 4 MB

#define SCOPE_AGENT __HIP_MEMORY_SCOPE_AGENT

// Cumulative barrier state in __device__ globals (zero-init at module load;
// monotone counters -> consistent across graph replays, never reset).
__device__ unsigned g_flags[NB];
__device__ unsigned g_gen;

__device__ __forceinline__ void grid_barrier(int b, int t, unsigned target) {
    __syncthreads();   // all waves' stores drained (vmcnt(0) before s_barrier)
    if (t < 64) {
        if (t == 0)    // publish this block's arrival + its global stores
            __hip_atomic_store(&g_flags[b], target, __ATOMIC_RELEASE, SCOPE_AGENT);
        if (b == 0) {
            // wave-parallel scan of all 256 flags, relaxed (no invalidates)
            for (int spin = 0; spin < (1 << 18); ++spin) {
                unsigned v0 = __hip_atomic_load(&g_flags[t],       __ATOMIC_RELAXED, SCOPE_AGENT);
                unsigned v1 = __hip_atomic_load(&g_flags[t + 64],  __ATOMIC_RELAXED, SCOPE_AGENT);
                unsigned v2 = __hip_atomic_load(&g_flags[t + 128], __ATOMIC_RELAXED, SCOPE_AGENT);
                unsigned v3 = __hip_atomic_load(&g_flags[t + 192], __ATOMIC_RELAXED, SCOPE_AGENT);
                bool ok = (v0 >= target) & (v1 >= target) &
                          (v2 >= target) & (v3 >= target);
                if (__all(ok)) break;
                __builtin_amdgcn_s_sleep(8);
            }
            if (t == 0)
                __hip_atomic_store(&g_gen, target, __ATOMIC_RELEASE, SCOPE_AGENT);
        } else if (t == 0) {
            for (int spin = 0; spin < (1 << 18); ++spin) {
                if (__hip_atomic_load(&g_gen, __ATOMIC_RELAXED, SCOPE_AGENT) >= target)
                    break;
                __builtin_amdgcn_s_sleep(8);
            }
        }
        // one acquire per block: invalidate stale L1/L2 before reading
        // other blocks' h1T/h2T
        __builtin_amdgcn_fence(__ATOMIC_ACQUIRE, "agent");
    }
    __syncthreads();
}

__global__ __launch_bounds__(NT, 4) void dwn_onekernel(
    const float* __restrict__ x,       // [512,1024]
    const float* __restrict__ thr,     // [1024,3]
    const float* __restrict__ luts1,   // [2000,64]
    const int*   __restrict__ idx1,    // [2000,6] in [0,3072)
    const float* __restrict__ luts2,   // [1000,64]
    const int*   __restrict__ idx2,    // [1000,6] in [0,2000)
    float* __restrict__ out,           // [512,10]
    unsigned long long* __restrict__ bitsT,  // [3072][8]
    float* __restrict__ h1T,                 // [2000][512]
    float* __restrict__ h2T)                 // [1000][512]
{
    const int t    = threadIdx.x;
    const int lane = t & 63;
    const int wl   = t >> 6;                 // wave in block, 0..15
    const int b    = blockIdx.x;
    const int gw   = (b << 4) | wl;          // global wave id, 0..4095

    // Cumulative barrier base: all flags are equal at launch (previous
    // launch completed all its barriers). Own-flag read only -> no race.
    unsigned base = 0;
    if (t < 64)
        base = __hip_atomic_load(&g_flags[b], __ATOMIC_RELAXED, SCOPE_AGENT);

    // ---- P1: thermometer encode + transposed bit-pack ----
    // Waves 0..7: rows 0..511 for features {4b,4b+1};
    // waves 8..15: same rows for features {4b+2,4b+3}.
    {
        const int w8    = wl & 7;
        const int row   = (w8 << 6) | lane;
        const int fbase = (b << 2) | ((wl >> 3) << 1);
#pragma unroll
        for (int ff = 0; ff < 2; ++ff) {
            const int f = fbase + ff;
            const float xv = x[(size_t)row * FEAT + f];
            const float* tp = thr + (size_t)f * 3;   // wave-uniform
#pragma unroll
            for (int j = 0; j < 3; ++j) {
                unsigned long long m = __ballot(xv > tp[j]);
                if (lane == 0)
                    bitsT[(size_t)(f * 3 + j) * 8 + w8] = m;
            }
        }
    }
    grid_barrier(b, t, base + 1);

    // ---- P2: layer 1 — binary inputs => pure 6-bit table lookup ----
    for (int task = gw; task < O1 * 8; task += NWAVES) {
        const int o = task >> 3;
        const int w = task & 7;
        const int* ip = idx1 + o * 6;        // wave-uniform

        const unsigned long long m0 = bitsT[(size_t)ip[0] * 8 + w];
        const unsigned long long m1 = bitsT[(size_t)ip[1] * 8 + w];
        const unsigned long long m2 = bitsT[(size_t)ip[2] * 8 + w];
        const unsigned long long m3 = bitsT[(size_t)ip[3] * 8 + w];
        const unsigned long long m4 = bitsT[(size_t)ip[4] * 8 + w];
        const unsigned long long m5 = bitsT[(size_t)ip[5] * 8 + w];

        const int code = ((int)((m0 >> lane) & 1ull) << 5)
                       | ((int)((m1 >> lane) & 1ull) << 4)
                       | ((int)((m2 >> lane) & 1ull) << 3)
                       | ((int)((m3 >> lane) & 1ull) << 2)
                       | ((int)((m4 >> lane) & 1ull) << 1)
                       |  (int)((m5 >> lane) & 1ull);

        h1T[(size_t)o * 512 + (w << 6) + lane] = luts1[o * 64 + code];
    }
    grid_barrier(b, t, base + 2);

    // ---- P3: layer 2 — 6-D multilinear interpolation, LSB-first fold ----
    // Arithmetic IDENTICAL (same lerp forms, same fold order) to the verified
    // kernel -> bitwise-equal output.
    for (int task = gw; task < O2 * 8; task += NWAVES) {
        const int o  = task >> 3;
        const int rr = ((task & 7) << 6) | lane;
        const int* ip = idx2 + o * 6;        // wave-uniform

        const float xv0 = h1T[(size_t)ip[0] * 512 + rr];
        const float xv1 = h1T[(size_t)ip[1] * 512 + rr];
        const float xv2 = h1T[(size_t)ip[2] * 512 + rr];
        const float xv3 = h1T[(size_t)ip[3] * 512 + rr];
        const float xv4 = h1T[(size_t)ip[4] * 512 + rr];
        const float xv5 = h1T[(size_t)ip[5] * 512 + rr];

        const float4* lp = (const float4*)(luts2 + (size_t)o * 64);  // uniform row
        float v[16];
#pragma unroll
        for (int q = 0; q < 16; ++q) {       // fold x5 (bit0), x4 (bit1)
            float4 e = lp[q];
            float u0 = e.x + xv5 * (e.y - e.x);
            float u1 = e.z + xv5 * (e.w - e.z);
            v[q] = u0 + xv4 * (u1 - u0);
        }
#pragma unroll
        for (int q = 0; q < 8; ++q) v[q] = v[2*q] + xv3 * (v[2*q+1] - v[2*q]);
#pragma unroll
        for (int q = 0; q < 4; ++q) v[q] = v[2*q] + xv2 * (v[2*q+1] - v[2*q]);
#pragma unroll
        for (int q = 0; q < 2; ++q) v[q] = v[2*q] + xv1 * (v[2*q+1] - v[2*q]);
        h2T[(size_t)o * 512 + rr] = v[0] + xv0 * (v[1] - v[0]);
    }
    grid_barrier(b, t, base + 3);

    // ---- P4: group sum / tau, exact 10x10 two-level order ----
    if (gw < NCLS * 8) {
        const int c  = gw >> 3;
        const int rr = ((gw & 7) << 6) | lane;
        const float* hp = h2T + (size_t)c * 100 * 512 + rr;

        float s = 0.0f;
#pragma unroll
        for (int p = 0; p < 10; ++p) {
            float s2 = 0.0f;
#pragma unroll
            for (int j = 0; j < 10; ++j) s2 += hp[(size_t)(p * 10 + j) * 512];
            s += s2;
        }
        out[rr * NCLS + c] = s / 3.3333333f;
    }
}

extern "C" void kernel_launch(void* const* d_in, const int* in_sizes, int n_in,
                              void* d_out, int out_size, void* d_ws, size_t ws_size,
                              hipStream_t stream) {
    const float* x     = (const float*)d_in[0];
    const float* thr   = (const float*)d_in[1];
    const float* luts1 = (const float*)d_in[2];
    const int*   idx1  = (const int*)  d_in[3];
    const float* luts2 = (const float*)d_in[4];
    const int*   idx2  = (const int*)  d_in[5];
    float* out = (float*)d_out;

    char* ws = (char*)d_ws;
    unsigned long long* bitsT = (unsigned long long*)(ws + WS_BITS_OFF);
    float* h1T = (float*)(ws + WS_H1_OFF);
    float* h2T = (float*)(ws + WS_H2_OFF);

    dwn_onekernel<<<NB, NT, 0, stream>>>(x, thr, luts1, idx1, luts2, idx2,
                                         out, bitsT, h1T, h2T);
}

// Round 5
// 78.556 us; speedup vs baseline: 2.1992x; 1.3716x over previous
//
#include <hip/hip_runtime.h>

// DWN pipeline, fully fused, block-local, ZERO grid barriers.
//
// Round-3/4 evidence: phases cost ~5us but every cross-XCD grid barrier
// costs ~13us irreducibly (agent-scope release/acquire = L2 writeback +
// invalidate across 8 non-coherent XCD L2s, x3 barriers -> 46.7us kernel).
// The dataflow is independent per batch row, so we revert to the round-0
// fused structure (block owns G=2 rows, all intermediates in LDS, only
// __syncthreads) and fix what actually made round-0 slow (~39us): it ran
// NT=512 = 2 waves/SIMD with serial dependent gather chains.
// Changes vs round-0:
//   - NT=1024 -> 16 waves/block = 4 waves/SIMD (2x latency hiding)
//   - thermometer bits bit-packed in LDS via __ballot (u32[96]/row),
//     thr read coalesced as flat [3072]
//   - P2 unrolled 4 tasks/thread, P3 2 tasks/thread -> independent idx
//     loads / LDS probes / LUT gathers issue concurrently (MLP)
//   - P3/P4 arithmetic bodies verbatim from the verified kernels
//     (same lerp forms, same fold order, same two-level sum) -> absmax 0.

#define BATCH 512
#define FEAT  1024
#define NBITS (FEAT * 3)      // 3072
#define O1    2000
#define O2    1000
#define NCLS  10
#define G     2               // batch rows per block
#define NB    (BATCH / G)     // 256 blocks
#define NT    1024            // 16 waves

__global__ __launch_bounds__(NT, 4) void dwn_fused(
    const float* __restrict__ x,       // [512,1024]
    const float* __restrict__ thr,     // [1024,3] == flat [3072]
    const float* __restrict__ luts1,   // [2000,64]
    const int*   __restrict__ idx1,    // [2000,6] in [0,3072)
    const float* __restrict__ luts2,   // [1000,64]
    const int*   __restrict__ idx2,    // [1000,6] in [0,2000)
    float* __restrict__ out)           // [512,10]
{
    __shared__ unsigned s_bw[G][NBITS / 32];   // 768 B, bit-packed thermo
    __shared__ float s_h1[G][O1];              // 16 KB
    __shared__ float s_h2[G][O2];              // 8 KB
    __shared__ float s_part[G * NCLS * 10];    // 800 B

    const int t    = threadIdx.x;
    const int lane = t & 63;
    const int wl   = t >> 6;                   // wave in block, 0..15
    const int b0   = blockIdx.x * G;

    // ---- P1: thermometer encode -> bit-packed LDS via ballot ----
    // 96 wave-tasks: (row r, 64-bit group g). bit index bi = g*64+lane,
    // feature f = bi/3, threshold thr[bi] (thr is exactly flat [f*3+j]).
#pragma unroll
    for (int k = 0; k < 6; ++k) {
        const int task = k * 16 + wl;          // 0..95, exact
        const int r  = task & 1;
        const int g  = task >> 1;              // 0..47
        const int bi = (g << 6) | lane;
        const int f  = bi / 3;                 // magic-mul
        const float xv = x[(b0 + r) * FEAT + f];
        const float tv = thr[bi];              // coalesced 256B/wave
        const unsigned long long m = __ballot(xv > tv);
        if (lane == 0) {
            s_bw[r][2 * g]     = (unsigned)m;
            s_bw[r][2 * g + 1] = (unsigned)(m >> 32);
        }
    }
    __syncthreads();

    // ---- P2: layer 1 — pure 6-bit table lookup ----
    // 4 unrolled tasks/thread; lane pairs (2j,2j+1) share o -> idx1/luts1
    // lines broadcast. Bit probe: word bi>>5, bit bi&31.
#pragma unroll
    for (int k = 0; k < 4; ++k) {
        const int i = t + k * NT;
        if (i < G * O1) {
            const int o = i >> 1;
            const int r = i & 1;
            const int2* ip = (const int2*)(idx1 + o * 6);  // o*24 is 8B-aligned
            const int2 p0 = ip[0], p1 = ip[1], p2 = ip[2];
            const int code =
                  ((int)((s_bw[r][p0.x >> 5] >> (p0.x & 31)) & 1u) << 5)
                | ((int)((s_bw[r][p0.y >> 5] >> (p0.y & 31)) & 1u) << 4)
                | ((int)((s_bw[r][p1.x >> 5] >> (p1.x & 31)) & 1u) << 3)
                | ((int)((s_bw[r][p1.y >> 5] >> (p1.y & 31)) & 1u) << 2)
                | ((int)((s_bw[r][p2.x >> 5] >> (p2.x & 31)) & 1u) << 1)
                |  (int)((s_bw[r][p2.y >> 5] >> (p2.y & 31)) & 1u);
            s_h1[r][o] = luts1[o * 64 + code];
        }
    }
    __syncthreads();

    // ---- P3: layer 2 — 6-D multilinear interpolation, LSB-first fold ----
    // Body verbatim from the verified kernel -> bitwise-equal output.
#pragma unroll
    for (int k = 0; k < 2; ++k) {
        const int i = t + k * NT;
        if (i < G * O2) {
            const int o = i >> 1;
            const int r = i & 1;
            const int2* ip = (const int2*)(idx2 + o * 6);
            const int2 p0 = ip[0], p1 = ip[1], p2 = ip[2];
            const float xv0 = s_h1[r][p0.x];
            const float xv1 = s_h1[r][p0.y];
            const float xv2 = s_h1[r][p1.x];
            const float xv3 = s_h1[r][p1.y];
            const float xv4 = s_h1[r][p2.x];
            const float xv5 = s_h1[r][p2.y];

            const float4* lp = (const float4*)(luts2 + (size_t)o * 64);
            float v[16];
#pragma unroll
            for (int q = 0; q < 16; ++q) {     // fold x5 (bit0), x4 (bit1)
                float4 e = lp[q];
                float u0 = e.x + xv5 * (e.y - e.x);
                float u1 = e.z + xv5 * (e.w - e.z);
                v[q] = u0 + xv4 * (u1 - u0);
            }
#pragma unroll
            for (int q = 0; q < 8; ++q) v[q] = v[2*q] + xv3 * (v[2*q+1] - v[2*q]);
#pragma unroll
            for (int q = 0; q < 4; ++q) v[q] = v[2*q] + xv2 * (v[2*q+1] - v[2*q]);
#pragma unroll
            for (int q = 0; q < 2; ++q) v[q] = v[2*q] + xv1 * (v[2*q+1] - v[2*q]);
            s_h2[r][o] = v[0] + xv0 * (v[1] - v[0]);
        }
    }
    __syncthreads();

    // ---- P4: group sum / tau, exact 10x10 two-level order (verbatim) ----
    if (t < G * NCLS * 10) {                   // 200 partial sums of 10
        int g = t / 10;
        int p = t % 10;
        int r   = g / NCLS;
        int cls = g % NCLS;
        const float* hp = &s_h2[r][cls * 100 + p * 10];
        float s = 0.0f;
#pragma unroll
        for (int j = 0; j < 10; ++j) s += hp[j];
        s_part[t] = s;
    }
    __syncthreads();
    if (t < G * NCLS) {                        // 20 final sums of 10 partials
        float s = 0.0f;
#pragma unroll
        for (int j = 0; j < 10; ++j) s += s_part[t * 10 + j];
        int r   = t / NCLS;
        int cls = t % NCLS;
        out[(b0 + r) * NCLS + cls] = s / 3.3333333f;
    }
}

extern "C" void kernel_launch(void* const* d_in, const int* in_sizes, int n_in,
                              void* d_out, int out_size, void* d_ws, size_t ws_size,
                              hipStream_t stream) {
    const float* x     = (const float*)d_in[0];
    const float* thr   = (const float*)d_in[1];
    const float* luts1 = (const float*)d_in[2];
    const int*   idx1  = (const int*)  d_in[3];
    const float* luts2 = (const float*)d_in[4];
    const int*   idx2  = (const int*)  d_in[5];
    float* out = (float*)d_out;

    dwn_fused<<<NB, NT, 0, stream>>>(x, thr, luts1, idx1, luts2, idx2, out);
}